// Round 1
// baseline (52890.198 us; speedup 1.0000x reference)
//
#include <hip/hip_runtime.h>

#define NTHREADS 512
#define NB 256
#define TT 64
#define NV 19

// LDS layout (floats, all 16B-aligned offsets):
//  Sm:364  h0:2432  h1:2432  cur:1904  xs:4864  m1:4864  m2:4864  gb:4864  cb:2432  = 29020 floats = 116KB

// ---- diffusion build: dst[n][0:256) = S @ src   (or 2*(S@src) - sub if sub != null)
// waves own n-slots {w, w+8, w+16}; 64 lanes cover the 256-float row as float4
__device__ __forceinline__ void diffuse(const float* Sm, const float* src, float* dst,
                                        const float* sub, int tid)
{
    const int wave = tid >> 6;
    const int c4 = (tid & 63) << 2;
    const int n0 = wave, n1 = wave + 8, n2 = wave + 16;
    float4 a0 = {0.f, 0.f, 0.f, 0.f};
    float4 a1 = {0.f, 0.f, 0.f, 0.f};
    float4 a2 = {0.f, 0.f, 0.f, 0.f};
#pragma unroll 1
    for (int m = 0; m < 19; ++m) {
        const float4 x4 = *(const float4*)(src + (m << 8) + c4);
        const float s0 = Sm[n0 * 19 + m];
        const float s1 = Sm[n1 * 19 + m];
        a0.x += s0 * x4.x; a0.y += s0 * x4.y; a0.z += s0 * x4.z; a0.w += s0 * x4.w;
        a1.x += s1 * x4.x; a1.y += s1 * x4.y; a1.z += s1 * x4.z; a1.w += s1 * x4.w;
        if (n2 < 19) {
            const float s2 = Sm[n2 * 19 + m];
            a2.x += s2 * x4.x; a2.y += s2 * x4.y; a2.z += s2 * x4.z; a2.w += s2 * x4.w;
        }
    }
    if (sub) {
        const float4 u0 = *(const float4*)(sub + (n0 << 8) + c4);
        const float4 u1 = *(const float4*)(sub + (n1 << 8) + c4);
        a0.x = 2.f * a0.x - u0.x; a0.y = 2.f * a0.y - u0.y;
        a0.z = 2.f * a0.z - u0.z; a0.w = 2.f * a0.w - u0.w;
        a1.x = 2.f * a1.x - u1.x; a1.y = 2.f * a1.y - u1.y;
        a1.z = 2.f * a1.z - u1.z; a1.w = 2.f * a1.w - u1.w;
        if (n2 < 19) {
            const float4 u2 = *(const float4*)(sub + (n2 << 8) + c4);
            a2.x = 2.f * a2.x - u2.x; a2.y = 2.f * a2.y - u2.y;
            a2.z = 2.f * a2.z - u2.z; a2.w = 2.f * a2.w - u2.w;
        }
    }
    *(float4*)(dst + (n0 << 8) + c4) = a0;
    *(float4*)(dst + (n1 << 8) + c4) = a1;
    if (n2 < 19) *(float4*)(dst + (n2 << 8) + c4) = a2;
}

// ---- out(19 x J) += [k-interleaved stack of xs,m1,m2](19 x 3D) @ W(3D x J)
// K split into 16 chunks of 16 padded rows: 8 waves x 2 half-wave teams.
// lane jg in [0,32): owns cols j = jt*32 + jg (stride-1 for conflict-free ds_add).
template <int JT, bool JG>
__device__ __forceinline__ void gemm_atomic(
    const float* xs, const float* m1, const float* m2,
    const float* __restrict__ W, int D, int J, int OSTR, float* outb, int tid)
{
    const int wave = tid >> 6;
    const int lane = tid & 63;
    const int jg = lane & 31;
    const int dbase = (((wave << 1) | (lane >> 5)) << 4);  // chunk * 16
    float acc[19 * JT];
#pragma unroll
    for (int i = 0; i < 19 * JT; ++i) acc[i] = 0.f;

#pragma unroll 1
    for (int g = 0; g < 4; ++g) {
        const int d0 = dbase + (g << 2);
#pragma unroll 1
        for (int kp = 0; kp < 3; ++kp) {
            const float* mat = (kp == 0) ? xs : ((kp == 1) ? m1 : m2);
            float w[4][JT];
#pragma unroll
            for (int r = 0; r < 4; ++r) {
                const int d = d0 + r;
                const long row = (long)(3 * d + kp) * J;
#pragma unroll
                for (int jt = 0; jt < JT; ++jt) {
                    const int jc = jt * 32 + jg;
                    const bool ok = (d < D) && (!JG || jc < J);
                    w[r][jt] = ok ? W[row + jc] : 0.f;
                }
            }
#pragma unroll
            for (int n = 0; n < 19; ++n) {
                const float4 x4 = *(const float4*)(mat + (n << 8) + d0);
#pragma unroll
                for (int jt = 0; jt < JT; ++jt) {
                    acc[n * JT + jt] += x4.x * w[0][jt];
                    acc[n * JT + jt] += x4.y * w[1][jt];
                    acc[n * JT + jt] += x4.z * w[2][jt];
                    acc[n * JT + jt] += x4.w * w[3][jt];
                }
            }
        }
    }
#pragma unroll
    for (int n = 0; n < 19; ++n)
#pragma unroll
        for (int jt = 0; jt < JT; ++jt) {
            const int jc = jt * 32 + jg;
            if (!JG || jc < J) atomicAdd(outb + n * OSTR + jc, acc[n * JT + jt]);
        }
}

// ---- projection GEMM: cb(19 x 100, stride 128) += h1(19 x 128) @ Wp(128 x 100)
__device__ __forceinline__ void proj_gemm(const float* h1, const float* __restrict__ Wp,
                                          float* outb, int tid)
{
    const int wave = tid >> 6;
    const int lane = tid & 63;
    const int jg = lane & 31;
    const int dbase = (((wave << 1) | (lane >> 5)) << 3);  // chunk * 8
    float acc[19 * 4];
#pragma unroll
    for (int i = 0; i < 19 * 4; ++i) acc[i] = 0.f;
#pragma unroll 1
    for (int g = 0; g < 2; ++g) {
        const int d0 = dbase + (g << 2);
        float w[4][4];
#pragma unroll
        for (int r = 0; r < 4; ++r) {
            const long row = (long)(d0 + r) * 100;
#pragma unroll
            for (int jt = 0; jt < 4; ++jt) {
                const int jc = jt * 32 + jg;
                w[r][jt] = (jc < 100) ? Wp[row + jc] : 0.f;
            }
        }
#pragma unroll
        for (int n = 0; n < 19; ++n) {
            const float4 x4 = *(const float4*)(h1 + (n << 7) + d0);
#pragma unroll
            for (int jt = 0; jt < 4; ++jt) {
                acc[n * 4 + jt] += x4.x * w[0][jt];
                acc[n * 4 + jt] += x4.y * w[1][jt];
                acc[n * 4 + jt] += x4.z * w[2][jt];
                acc[n * 4 + jt] += x4.w * w[3][jt];
            }
        }
    }
#pragma unroll
    for (int n = 0; n < 19; ++n)
#pragma unroll
        for (int jt = 0; jt < 4; ++jt) {
            const int jc = jt * 32 + jg;
            if (jc < 100) atomicAdd(outb + (n << 7) + jc, acc[n * 4 + jt]);
        }
}

// ---- one DCGRU cell: h <- u*h + (1-u)*tanh(dconv(x, r*h))
__device__ __forceinline__ void cell(
    int Dx, const float* x, float* h,
    const float* __restrict__ Wg, const float* __restrict__ bg,
    const float* __restrict__ Wc, const float* __restrict__ bc,
    const float* Sm, float* xs, float* m1, float* m2, float* gb, float* cb, int tid)
{
    const int D = Dx + 128;
    // stage xs = [x | h], zero-pad to 256; init gates buffer with bias
    for (int i = tid; i < NV * 256; i += NTHREADS) {
        const int n = i >> 8, d = i & 255;
        float v = 0.f;
        if (d < Dx) v = x[n * Dx + d];
        else if (d < D) v = h[(n << 7) + (d - Dx)];
        xs[i] = v;
        gb[i] = bg[d];
    }
    __syncthreads();
    diffuse(Sm, xs, m1, nullptr, tid);
    __syncthreads();
    diffuse(Sm, m1, m2, xs, tid);
    __syncthreads();
    gemm_atomic<8, false>(xs, m1, m2, Wg, D, 256, 256, gb, tid);
    __syncthreads();
    // sigmoid; write r*h into xs h-part; init cand buffer with bias
    for (int i = tid; i < NV * 256; i += NTHREADS) {
        const int n = i >> 8, j = i & 255;
        const float sg = 1.f / (1.f + __expf(-gb[i]));
        gb[i] = sg;
        if (j < 128) {
            xs[(n << 8) + Dx + j] = sg * h[(n << 7) + j];
            cb[(n << 7) + j] = bc[j];
        }
    }
    __syncthreads();
    diffuse(Sm, xs, m1, nullptr, tid);
    __syncthreads();
    diffuse(Sm, m1, m2, xs, tid);
    __syncthreads();
    gemm_atomic<4, false>(xs, m1, m2, Wc, D, 128, 128, cb, tid);
    __syncthreads();
    // h update: u in gb[:,128:256], c = tanh(cb)
    for (int i = tid; i < NV * 128; i += NTHREADS) {
        const int n = i >> 7, j = i & 127;
        const float u = gb[(n << 8) + 128 + j];
        const float e = __expf(-2.f * cb[i]);
        const float cv = (1.f - e) / (1.f + e);
        h[i] = u * h[i] + (1.f - u) * cv;
    }
    __syncthreads();
}

__global__ __launch_bounds__(NTHREADS, 2) void dcrnn_kernel(
    const float* __restrict__ enc, const float* __restrict__ sup,
    const float* e0Wg, const float* e0bg, const float* e0Wc, const float* e0bc,
    const float* e1Wg, const float* e1bg, const float* e1Wc, const float* e1bc,
    const float* d0Wg, const float* d0bg, const float* d0Wc, const float* d0bc,
    const float* d1Wg, const float* d1bg, const float* d1Wc, const float* d1bc,
    const float* Wp, const float* bp, float* __restrict__ out)
{
    __shared__ __align__(16) float lds[29020];
    float* Sm  = lds;           // 364
    float* h0  = Sm + 364;      // 2432
    float* h1  = h0 + 2432;     // 2432
    float* cur = h1 + 2432;     // 1904
    float* xs  = cur + 1904;    // 4864
    float* m1  = xs + 4864;     // 4864
    float* m2  = m1 + 4864;     // 4864
    float* gb  = m2 + 4864;     // 4864
    float* cb  = gb + 4864;     // 2432

    const int tid = threadIdx.x;
    const int b = blockIdx.x;

    for (int i = tid; i < 361; i += NTHREADS) Sm[i] = sup[i];
    for (int i = tid; i < 2432; i += NTHREADS) { h0[i] = 0.f; h1[i] = 0.f; }
    for (int i = tid; i < 1900; i += NTHREADS) cur[i] = 0.f;
    __syncthreads();

    // encoder: two stacked DCGRU layers, interleaved per timestep
    for (int t = 0; t < TT; ++t) {
        const float* xg = enc + ((size_t)b * TT + t) * (NV * 100);
        cell(100, xg, h0, e0Wg, e0bg, e0Wc, e0bc, Sm, xs, m1, m2, gb, cb, tid);
        cell(128, h0, h1, e1Wg, e1bg, e1Wc, e1bc, Sm, xs, m1, m2, gb, cb, tid);
    }
    // decoder: autoregressive, feedback through LDS `cur`
    for (int t = 0; t < TT; ++t) {
        cell(100, cur, h0, d0Wg, d0bg, d0Wc, d0bc, Sm, xs, m1, m2, gb, cb, tid);
        cell(128, h0, h1, d1Wg, d1bg, d1Wc, d1bc, Sm, xs, m1, m2, gb, cb, tid);
        // projection: proj = h1 @ Wp + bp  (into cb, stride 128)
        for (int i = tid; i < NV * 128; i += NTHREADS) {
            const int o = i & 127;
            cb[i] = (o < 100) ? bp[o] : 0.f;
        }
        __syncthreads();
        proj_gemm(h1, Wp, cb, tid);
        __syncthreads();
        float* po = out + ((size_t)b * TT + t) * (NV * 100);
        for (int i = tid; i < NV * 100; i += NTHREADS) {
            const int n = i / 100;
            const int o = i - n * 100;
            const float v = cb[(n << 7) + o];
            po[i] = v;
            cur[i] = v;
        }
        __syncthreads();
    }
}

extern "C" void kernel_launch(void* const* d_in, const int* in_sizes, int n_in,
                              void* d_out, int out_size, void* d_ws, size_t ws_size,
                              hipStream_t stream)
{
    const float* enc  = (const float*)d_in[0];
    // d_in[1] = decoder_inputs: values unused by the reference (autoregressive feedback)
    const float* sup  = (const float*)d_in[2];
    const float* e0Wg = (const float*)d_in[3];
    const float* e0bg = (const float*)d_in[4];
    const float* e0Wc = (const float*)d_in[5];
    const float* e0bc = (const float*)d_in[6];
    const float* e1Wg = (const float*)d_in[7];
    const float* e1bg = (const float*)d_in[8];
    const float* e1Wc = (const float*)d_in[9];
    const float* e1bc = (const float*)d_in[10];
    const float* d0Wg = (const float*)d_in[11];
    const float* d0bg = (const float*)d_in[12];
    const float* d0Wc = (const float*)d_in[13];
    const float* d0bc = (const float*)d_in[14];
    const float* d1Wg = (const float*)d_in[15];
    const float* d1bg = (const float*)d_in[16];
    const float* d1Wc = (const float*)d_in[17];
    const float* d1bc = (const float*)d_in[18];
    const float* Wp   = (const float*)d_in[19];
    const float* bp   = (const float*)d_in[20];

    dcrnn_kernel<<<dim3(NB), dim3(NTHREADS), 0, stream>>>(
        enc, sup,
        e0Wg, e0bg, e0Wc, e0bc, e1Wg, e1bg, e1Wc, e1bc,
        d0Wg, d0bg, d0Wc, d0bc, d1Wg, d1bg, d1Wc, d1bc,
        Wp, bp, (float*)d_out);
}